// Round 6
// baseline (132.242 us; speedup 1.0000x reference)
//
#include <hip/hip_runtime.h>
#include <stdint.h>

// Problem constants
#define NPTS     200000
#define MAXP     35
#define MAXVOX   200000
#define GYZ      64000
#define GZD      40
#define TOTALLIN 90112000u        // invalid-point lin marker (== TOTAL in reference)

// Output layout (flat float32): features [200000*35*4] | coords [200000*3] | num [200000]
#define OFF_COORD 28000000
#define OFF_NUM   28600000

// Bucket sort params: top 11 bits of biased key -> 2048 buckets, ~98 avg
#define NBUK   2048
#define BCAP   256

// ws layout (uint32 words)
#define WS_PLIN     0              // 200000
#define WS_UKEY     200000         // 200000
#define WS_BCNT     400000         // 2048
#define WS_BSTART   402048         // 2048
#define WS_BCUR     404096         // 2048
#define WS_PAIR     406144         // 200000 uint64 = 400000 words (8B-aligned)
#define WS_ORD      806144         // 200000
#define WS_LINS     1006144        // 200000
#define WS_SARR     1206144        // 200000
#define WS_SINC     1406144        // 200000
#define WS_BS2      1606144        // 256
#define WS_FIRSTPOS 1606400        // 200000
#define WS_ULIN     1806400        // 200000
#define WS_CNT      2006400        // 200000
#define WS_DIAG     2206400        // 16
#define WS_WORDS_NEEDED 2206416    // 8,825,664 bytes

// Voxel id with XLA-simplifier semantics: (p - rmin) / vs rewritten to
// (p - rmin) * (1/vs); f32 reciprocals of 0.05f / 0.1f fold to EXACTLY 20.0f / 10.0f.
__device__ __forceinline__ uint32_t point_lin(const float4 p) {
    float fx = floorf((p.x -  0.0f) * 20.0f);
    float fy = floorf((p.y + 40.0f) * 20.0f);
    float fz = floorf((p.z +  3.0f) * 10.0f);
    if (fx < 0.0f || fx >= 1408.0f || fy < 0.0f || fy >= 1600.0f ||
        fz < 0.0f || fz >= 40.0f)
        return TOTALLIN;
    return (uint32_t)fx * (uint32_t)GYZ + (uint32_t)fy * (uint32_t)GZD + (uint32_t)fz;
}

// 1) per-point lin + wrapped int32 sort key (jax x64-OFF semantics) + bucket histogram
__global__ void k_key(const float4* __restrict__ pts, uint32_t* __restrict__ plin,
                      uint32_t* __restrict__ ukey, uint32_t* __restrict__ bcnt) {
    int i = blockIdx.x * blockDim.x + threadIdx.x;
    if (i >= NPTS) return;
    uint32_t lin = point_lin(pts[i]);
    plin[i] = lin;
    uint32_t key = lin * 200000u + (uint32_t)i;   // int32 wrap, bit-identical in uint32
    uint32_t uk = key ^ 0x80000000u;              // biased: unsigned order == signed order
    ukey[i] = uk;
    atomicAdd(&bcnt[uk >> 21], 1u);
}

// 2) exclusive scan of 2048 bucket counts (1 block, 8 chunks of 256)
__global__ void k_bscan(const uint32_t* __restrict__ bcnt, uint32_t* __restrict__ bstart) {
    __shared__ uint32_t s[256];
    __shared__ uint32_t run;
    int t = threadIdx.x;
    if (t == 0) run = 0;
    __syncthreads();
    for (int c = 0; c < NBUK / 256; c++) {
        int idx = c * 256 + t;
        uint32_t v = bcnt[idx];
        s[t] = v; __syncthreads();
        for (int off = 1; off < 256; off <<= 1) {
            uint32_t x = (t >= off) ? s[t - off] : 0u;
            __syncthreads();
            s[t] += x; __syncthreads();
        }
        uint32_t incl = s[t];
        uint32_t tot  = s[255];
        uint32_t r    = run;
        bstart[idx] = r + incl - v;
        __syncthreads();
        if (t == 0) run = r + tot;
        __syncthreads();
    }
}

// 3) scatter (ukey, idx) pairs into buckets (arbitrary intra-bucket order)
__global__ void k_scatter(const uint32_t* __restrict__ ukey, const uint32_t* __restrict__ bstart,
                          uint32_t* __restrict__ bcur, unsigned long long* __restrict__ pair,
                          uint32_t* __restrict__ diag) {
    int i = blockIdx.x * blockDim.x + threadIdx.x;
    if (i >= NPTS) return;
    uint32_t uk = ukey[i];
    uint32_t b = uk >> 21;
    uint32_t j = atomicAdd(&bcur[b], 1u);
    if (j < BCAP)
        pair[bstart[b] + j] = ((unsigned long long)uk << 32) | (uint32_t)i;
    else
        atomicOr(&diag[0], 2u);   // bucket overflow -> loud failure
}

// 4) per-bucket odd-even transposition sort in LDS (stable: single u64 key (uk,i))
__global__ __launch_bounds__(128) void k_bsort(const uint32_t* __restrict__ bcnt,
                                               const uint32_t* __restrict__ bstart,
                                               unsigned long long* __restrict__ pair,
                                               const uint32_t* __restrict__ plin,
                                               uint32_t* __restrict__ ord,
                                               uint32_t* __restrict__ lin_s) {
    __shared__ unsigned long long sd[BCAP];
    int b = blockIdx.x, t = threadIdx.x;
    int n = (int)bcnt[b];
    if (n > BCAP) n = BCAP;
    int base = (int)bstart[b];
    for (int k = t; k < n; k += 128) sd[k] = pair[base + k];
    __syncthreads();
    for (int ph = 0; ph < n; ph++) {
        int idx = 2 * t + (ph & 1);
        if (idx + 1 < n) {
            unsigned long long a = sd[idx], c = sd[idx + 1];
            if (a > c) { sd[idx] = c; sd[idx + 1] = a; }
        }
        __syncthreads();
    }
    for (int k = t; k < n; k += 128) {
        unsigned long long v = sd[k];
        uint32_t i = (uint32_t)v;
        pair[base + k] = v;               // sorted, for the global check
        ord[base + k] = i;
        lin_s[base + k] = plin[i];
    }
}

// 5) global strict-sortedness check (keys unique); any violation -> flag 4
__global__ void k_sortcheck(const unsigned long long* __restrict__ pair, uint32_t* __restrict__ diag) {
    int pos = blockIdx.x * blockDim.x + threadIdx.x;
    if (pos < 1 || pos >= NPTS) return;
    if (pair[pos] <= pair[pos - 1]) atomicOr(&diag[0], 4u);
}

// 6) segment heads (reference: is_first = valid & new_seg) on the WRAPPED order
__global__ void k_seg(const uint32_t* __restrict__ lin_s, uint32_t* __restrict__ sarr) {
    int pos = blockIdx.x * blockDim.x + threadIdx.x;
    if (pos >= NPTS) return;
    uint32_t lin = lin_s[pos];
    bool valid = (lin != TOTALLIN);
    bool nseg = (pos == 0) || (lin != lin_s[pos - 1]);
    sarr[pos] = (valid && nseg) ? 1u : 0u;
}

// 7a) per-block(1024) local inclusive scan + block sums
__global__ void k_s1(const uint32_t* __restrict__ sarr, uint32_t* __restrict__ sinc,
                     uint32_t* __restrict__ bs2) {
    __shared__ uint32_t s[256];
    int b = blockIdx.x, t = threadIdx.x;
    int base = b * 1024 + t * 4;
    uint32_t x0 = (base + 0 < NPTS) ? sarr[base + 0] : 0u;
    uint32_t x1 = (base + 1 < NPTS) ? sarr[base + 1] : 0u;
    uint32_t x2 = (base + 2 < NPTS) ? sarr[base + 2] : 0u;
    uint32_t x3 = (base + 3 < NPTS) ? sarr[base + 3] : 0u;
    uint32_t tsum = x0 + x1 + x2 + x3;
    s[t] = tsum; __syncthreads();
    for (int off = 1; off < 256; off <<= 1) {
        uint32_t x = (t >= off) ? s[t - off] : 0u;
        __syncthreads();
        s[t] += x; __syncthreads();
    }
    uint32_t incl = s[t];
    uint32_t running = incl - tsum;
    running += x0; if (base + 0 < NPTS) sinc[base + 0] = running;
    running += x1; if (base + 1 < NPTS) sinc[base + 1] = running;
    running += x2; if (base + 2 < NPTS) sinc[base + 2] = running;
    running += x3; if (base + 3 < NPTS) sinc[base + 3] = running;
    if (t == 255) bs2[b] = incl;
}

// 7b) scan 196 block sums -> exclusive offsets (1 block)
__global__ void k_s2(uint32_t* __restrict__ bs2, int nb) {
    __shared__ uint32_t s[256];
    int t = threadIdx.x;
    uint32_t v = (t < nb) ? bs2[t] : 0u;
    s[t] = v; __syncthreads();
    for (int off = 1; off < 256; off <<= 1) {
        uint32_t x = (t >= off) ? s[t - off] : 0u;
        __syncthreads();
        s[t] += x; __syncthreads();
    }
    if (t < nb) bs2[t] = s[t] - v;
}

// 7c) add block offsets
__global__ void k_s3(uint32_t* __restrict__ sinc, const uint32_t* __restrict__ bs2) {
    int b = blockIdx.x, t = threadIdx.x;
    int base = b * 1024 + t * 4;
    uint32_t off = bs2[b];
#pragma unroll
    for (int j = 0; j < 4; j++)
        if (base + j < NPTS) sinc[base + j] += off;
}

// 8) record segment firsts: firstpos[slot], ulin[slot]
__global__ void k_first(const uint32_t* __restrict__ sarr, const uint32_t* __restrict__ sinc,
                        const uint32_t* __restrict__ lin_s, uint32_t* __restrict__ firstpos,
                        uint32_t* __restrict__ ulin) {
    int pos = blockIdx.x * blockDim.x + threadIdx.x;
    if (pos >= NPTS) return;
    if (sarr[pos]) {
        uint32_t slot = sinc[pos] - 1u;
        if (slot < MAXVOX) { firstpos[slot] = (uint32_t)pos; ulin[slot] = lin_s[pos]; }
    }
}

// 9) emit features + counts (features region pre-zeroed by memset)
__global__ void k_emit(const float4* __restrict__ pts, const uint32_t* __restrict__ lin_s,
                       const uint32_t* __restrict__ sinc, const uint32_t* __restrict__ firstpos,
                       const uint32_t* __restrict__ ord, uint32_t* __restrict__ cnt,
                       float* __restrict__ out) {
    int pos = blockIdx.x * blockDim.x + threadIdx.x;
    if (pos >= NPTS) return;
    uint32_t lin = lin_s[pos];
    if (lin == TOTALLIN) return;
    uint32_t slot = sinc[pos] - 1u;
    if (slot >= MAXVOX) return;
    uint32_t rank = (uint32_t)pos - firstpos[slot];
    if (rank >= MAXP) return;
    const float* pp = reinterpret_cast<const float*>(pts + ord[pos]);
    float* fo = out + (size_t)slot * (MAXP * 4) + (size_t)rank * 4;
    fo[0] = pp[0]; fo[1] = pp[1]; fo[2] = pp[2]; fo[3] = pp[3];
    atomicAdd(&cnt[slot], 1u);
}

// 10) coords + num for every slot (ulin/cnt are zero for padding slots)
__global__ void k_writeAll(const uint32_t* __restrict__ cnt, const uint32_t* __restrict__ ulin,
                           float* __restrict__ out) {
    int slot = blockIdx.x * blockDim.x + threadIdx.x;
    if (slot >= MAXVOX) return;
    uint32_t L = ulin[slot];
    out[OFF_COORD + (size_t)slot * 3 + 0] = (float)(L / GYZ);
    out[OFF_COORD + (size_t)slot * 3 + 1] = (float)((L % GYZ) / GZD);
    out[OFF_COORD + (size_t)slot * 3 + 2] = (float)(L % GZD);
    out[OFF_NUM + slot] = (float)cnt[slot];
}

// 11) loud failure channel
__global__ void k_diag3(const uint32_t* __restrict__ diag, float* __restrict__ out) {
    uint32_t f = diag[0];
    if (f != 0u) out[0] = (float)f * 1e8f;
}

__global__ void k_sentinel(float* __restrict__ out) { out[0] = 1e8f; }

extern "C" void kernel_launch(void* const* d_in, const int* in_sizes, int n_in,
                              void* d_out, int out_size, void* d_ws, size_t ws_size,
                              hipStream_t stream) {
    const float4* pts = (const float4*)d_in[0];
    float* out = (float*)d_out;
    uint32_t* ws = (uint32_t*)d_ws;

    if (ws_size < (size_t)WS_WORDS_NEEDED * sizeof(uint32_t)) {
        k_sentinel<<<1, 1, 0, stream>>>(out);
        return;
    }

    uint32_t* plin     = ws + WS_PLIN;
    uint32_t* ukey     = ws + WS_UKEY;
    uint32_t* bcnt     = ws + WS_BCNT;
    uint32_t* bstart   = ws + WS_BSTART;
    uint32_t* bcur     = ws + WS_BCUR;
    unsigned long long* pair = (unsigned long long*)(ws + WS_PAIR);
    uint32_t* ord      = ws + WS_ORD;
    uint32_t* lin_s    = ws + WS_LINS;
    uint32_t* sarr     = ws + WS_SARR;
    uint32_t* sinc     = ws + WS_SINC;
    uint32_t* bs2      = ws + WS_BS2;
    uint32_t* firstpos = ws + WS_FIRSTPOS;
    uint32_t* ulin     = ws + WS_ULIN;
    uint32_t* cnt      = ws + WS_CNT;
    uint32_t* diag     = ws + WS_DIAG;

    const int NBLK = (NPTS + 255) / 256;       // 782
    const int NSB  = (NPTS + 1023) / 1024;     // 196

    hipMemsetAsync(out, 0, (size_t)out_size * sizeof(float), stream);
    hipMemsetAsync(bcnt, 0, (size_t)(3 * NBUK) * sizeof(uint32_t), stream);          // bcnt+bstart+bcur
    hipMemsetAsync(ulin, 0, (size_t)(2 * MAXVOX + 16) * sizeof(uint32_t), stream);   // ulin+cnt+diag

    k_key<<<NBLK, 256, 0, stream>>>(pts, plin, ukey, bcnt);
    k_bscan<<<1, 256, 0, stream>>>(bcnt, bstart);
    k_scatter<<<NBLK, 256, 0, stream>>>(ukey, bstart, bcur, pair, diag);
    k_bsort<<<NBUK, 128, 0, stream>>>(bcnt, bstart, pair, plin, ord, lin_s);
    k_sortcheck<<<NBLK, 256, 0, stream>>>(pair, diag);
    k_seg<<<NBLK, 256, 0, stream>>>(lin_s, sarr);
    k_s1<<<NSB, 256, 0, stream>>>(sarr, sinc, bs2);
    k_s2<<<1, 256, 0, stream>>>(bs2, NSB);
    k_s3<<<NSB, 256, 0, stream>>>(sinc, bs2);
    k_first<<<NBLK, 256, 0, stream>>>(sarr, sinc, lin_s, firstpos, ulin);
    k_emit<<<NBLK, 256, 0, stream>>>(pts, lin_s, sinc, firstpos, ord, cnt, out);
    k_writeAll<<<NBLK, 256, 0, stream>>>(cnt, ulin, out);
    k_diag3<<<1, 1, 0, stream>>>(diag, out);
}

// Round 7
// 119.369 us; speedup vs baseline: 1.1078x; 1.1078x over previous
//
#include <hip/hip_runtime.h>
#include <stdint.h>

// Problem constants
#define NPTS     200000
#define MAXP     35
#define MAXVOX   200000
#define GYZ      64000
#define GZD      40
#define TOTALLIN 90112000u        // invalid-point lin marker (== TOTAL in reference)

// Output layout (flat float32): features [200000*35*4] | coords [200000*3] | num [200000]
#define OFF_COORD 28000000
#define OFF_NUM   28600000

#define NBUK   2048               // top-11-bit buckets of biased wrapped key
#define BCAP   256                // max bucket occupancy (measured ~98 avg, pass at 256)
#define NROWS  (MAXVOX * MAXP)    // 7,000,000 feature rows, one float4 each

// ws layout (uint32 words)
#define WS_PLIN   0               // 200000
#define WS_UKEY   200000          // 200000
#define WS_BCNT   400000          // 2048
#define WS_BSTART 402048          // 2048
#define WS_BCUR   404096          // 2048
#define WS_PAIR   406144          // 200000 u64 = 400000 words (8B-aligned)
#define WS_ORD    806144          // 200000
#define WS_LINS   1006144         // 200000
#define WS_SINC   1206144         // 200000
#define WS_BS2    1406144         // 256 ([255] = nunique)
#define WS_FIRST  1406400         // 200000
#define WS_ULIN   1606400         // 200000 (kept for debug symmetry; coords now from lin)
#define WS_CNT    1806400         // 200000
#define WS_WORDS  2006400         // 8,025,600 bytes

// Voxel id with XLA-simplifier semantics: (p-rmin)/vs -> (p-rmin)*(1/vs);
// f32 reciprocals of 0.05f / 0.1f constant-fold to EXACTLY 20.0f / 10.0f.
__device__ __forceinline__ uint32_t point_lin(const float4 p) {
    float fx = floorf((p.x -  0.0f) * 20.0f);
    float fy = floorf((p.y + 40.0f) * 20.0f);
    float fz = floorf((p.z +  3.0f) * 10.0f);
    if (fx < 0.0f || fx >= 1408.0f || fy < 0.0f || fy >= 1600.0f ||
        fz < 0.0f || fz >= 40.0f)
        return TOTALLIN;
    return (uint32_t)fx * (uint32_t)GYZ + (uint32_t)fy * (uint32_t)GZD + (uint32_t)fz;
}

// 1) per-point lin + wrapped int32 sort key (jax x64-OFF) + bucket histogram
__global__ void k_key(const float4* __restrict__ pts, uint32_t* __restrict__ plin,
                      uint32_t* __restrict__ ukey, uint32_t* __restrict__ bcnt) {
    int i = blockIdx.x * blockDim.x + threadIdx.x;
    if (i >= NPTS) return;
    uint32_t lin = point_lin(pts[i]);
    plin[i] = lin;
    uint32_t key = lin * 200000u + (uint32_t)i;   // int32 wrap, bit-identical in uint32
    uint32_t uk = key ^ 0x80000000u;              // bias: unsigned order == signed order
    ukey[i] = uk;
    atomicAdd(&bcnt[uk >> 21], 1u);
}

// 2) exclusive scan of 2048 bucket counts (1 block)
__global__ void k_bscan(const uint32_t* __restrict__ bcnt, uint32_t* __restrict__ bstart) {
    __shared__ uint32_t s[256];
    __shared__ uint32_t run;
    int t = threadIdx.x;
    if (t == 0) run = 0;
    __syncthreads();
    for (int c = 0; c < NBUK / 256; c++) {
        int idx = c * 256 + t;
        uint32_t v = bcnt[idx];
        s[t] = v; __syncthreads();
        for (int off = 1; off < 256; off <<= 1) {
            uint32_t x = (t >= off) ? s[t - off] : 0u;
            __syncthreads();
            s[t] += x; __syncthreads();
        }
        uint32_t incl = s[t];
        uint32_t tot  = s[255];
        uint32_t r    = run;
        bstart[idx] = r + incl - v;
        __syncthreads();
        if (t == 0) run = r + tot;
        __syncthreads();
    }
}

// 3) scatter (ukey, idx) pairs into buckets
__global__ void k_scatter(const uint32_t* __restrict__ ukey, const uint32_t* __restrict__ bstart,
                          uint32_t* __restrict__ bcur, unsigned long long* __restrict__ pair) {
    int i = blockIdx.x * blockDim.x + threadIdx.x;
    if (i >= NPTS) return;
    uint32_t uk = ukey[i];
    uint32_t b = uk >> 21;
    uint32_t j = atomicAdd(&bcur[b], 1u);
    if (j < BCAP)
        pair[bstart[b] + j] = ((unsigned long long)uk << 32) | (uint32_t)i;
}

// 4) per-bucket bitonic sort of 256 padded u64 keys (keys unique -> stability moot)
__global__ __launch_bounds__(128) void k_bsort(const uint32_t* __restrict__ bcnt,
                                               const uint32_t* __restrict__ bstart,
                                               const unsigned long long* __restrict__ pair,
                                               const uint32_t* __restrict__ plin,
                                               uint32_t* __restrict__ ord,
                                               uint32_t* __restrict__ lin_s) {
    __shared__ unsigned long long sd[BCAP];
    int b = blockIdx.x, t = threadIdx.x;
    int n = (int)bcnt[b];
    if (n > BCAP) n = BCAP;
    int base = (int)bstart[b];
    for (int k = t; k < BCAP; k += 128)
        sd[k] = (k < n) ? pair[base + k] : ~0ULL;
    __syncthreads();
    for (int k = 2; k <= BCAP; k <<= 1) {
        for (int j = k >> 1; j > 0; j >>= 1) {
            int i = ((t & ~(j - 1)) << 1) | (t & (j - 1));
            int p = i | j;
            bool up = ((i & k) == 0);
            unsigned long long a = sd[i], c = sd[p];
            if ((a > c) == up) { sd[i] = c; sd[p] = a; }
            __syncthreads();
        }
    }
    for (int k = t; k < n; k += 128) {
        unsigned long long v = sd[k];
        uint32_t i = (uint32_t)v;
        ord[base + k] = i;
        lin_s[base + k] = plin[i];
    }
}

// 5) fused head-flag + per-1024-block inclusive scan (sinc local) + block sums
__global__ void k_s1(const uint32_t* __restrict__ lin_s, uint32_t* __restrict__ sinc,
                     uint32_t* __restrict__ bs2) {
    __shared__ uint32_t s[256];
    int b = blockIdx.x, t = threadIdx.x;
    int base = b * 1024 + t * 4;
    uint32_t f[4];
    uint32_t prev = (base > 0 && base - 1 < NPTS) ? lin_s[base - 1] : 0xFFFFFFFFu;
    uint32_t tsum = 0;
#pragma unroll
    for (int j = 0; j < 4; j++) {
        int pos = base + j;
        f[j] = 0u;
        if (pos < NPTS) {
            uint32_t lin = lin_s[pos];
            bool head = (lin != TOTALLIN) && (pos == 0 || lin != prev);
            f[j] = head ? 1u : 0u;
            prev = lin;
        }
        tsum += f[j];
    }
    s[t] = tsum; __syncthreads();
    for (int off = 1; off < 256; off <<= 1) {
        uint32_t x = (t >= off) ? s[t - off] : 0u;
        __syncthreads();
        s[t] += x; __syncthreads();
    }
    uint32_t incl = s[t];
    uint32_t running = incl - tsum;
#pragma unroll
    for (int j = 0; j < 4; j++) {
        int pos = base + j;
        running += f[j];
        if (pos < NPTS) sinc[pos] = running;   // local inclusive within 1024-block
    }
    if (t == 255) bs2[b] = incl;               // block total
}

// 6) exclusive scan of 196 block sums; [255] <- nunique
__global__ void k_s2(uint32_t* __restrict__ bs2, int nb) {
    __shared__ uint32_t s[256];
    int t = threadIdx.x;
    uint32_t v = (t < nb) ? bs2[t] : 0u;
    s[t] = v; __syncthreads();
    for (int off = 1; off < 256; off <<= 1) {
        uint32_t x = (t >= off) ? s[t - off] : 0u;
        __syncthreads();
        s[t] += x; __syncthreads();
    }
    if (t == nb - 1) bs2[255] = s[t];          // total heads = nunique
    if (t < nb) bs2[t] = s[t] - v;             // exclusive offset
}

// 7) heads: slot id, run length, firstpos/cnt; write coords+num (real + padding)
__global__ void k_first(const uint32_t* __restrict__ lin_s, const uint32_t* __restrict__ sinc,
                        const uint32_t* __restrict__ bs2, uint32_t* __restrict__ firstpos,
                        uint32_t* __restrict__ cnt, float* __restrict__ out) {
    int pos = blockIdx.x * blockDim.x + threadIdx.x;
    if (pos >= NPTS) return;
    uint32_t nun = bs2[255];
    if ((uint32_t)pos >= nun) {                // padding slots (slot space == pos space)
        out[OFF_COORD + (size_t)pos * 3 + 0] = 0.0f;
        out[OFF_COORD + (size_t)pos * 3 + 1] = 0.0f;
        out[OFF_COORD + (size_t)pos * 3 + 2] = 0.0f;
        out[OFF_NUM + pos] = 0.0f;
    }
    uint32_t lin = lin_s[pos];
    if (lin == TOTALLIN) return;
    if (pos > 0 && lin == lin_s[pos - 1]) return;          // not a head
    uint32_t slot = sinc[pos] + bs2[pos >> 10] - 1u;
    int n = 1;
    while (pos + n < NPTS && lin_s[pos + n] == lin) ++n;   // run length (short segments)
    firstpos[slot] = (uint32_t)pos;
    cnt[slot] = (uint32_t)n;
    int m = (n < MAXP) ? n : MAXP;
    out[OFF_COORD + (size_t)slot * 3 + 0] = (float)(lin / GYZ);
    out[OFF_COORD + (size_t)slot * 3 + 1] = (float)((lin % GYZ) / GZD);
    out[OFF_COORD + (size_t)slot * 3 + 2] = (float)(lin % GZD);
    out[OFF_NUM + slot] = (float)m;
}

// 8) features: one thread per row (= one float4); writes EVERY row exactly once
__global__ void k_writeF(const float4* __restrict__ pts, const uint32_t* __restrict__ firstpos,
                         const uint32_t* __restrict__ cnt, const uint32_t* __restrict__ ord,
                         const uint32_t* __restrict__ bs2, float4* __restrict__ outF) {
    int row = blockIdx.x * blockDim.x + threadIdx.x;
    if (row >= NROWS) return;
    uint32_t slot = (uint32_t)row / 35u;       // magic-mul const division
    uint32_t r = (uint32_t)row - slot * 35u;
    uint32_t nun = bs2[255];
    float4 v = make_float4(0.0f, 0.0f, 0.0f, 0.0f);
    if (slot < nun) {
        uint32_t n = cnt[slot];
        if (r < n)                              // r<=34 so r<n  <=>  r<min(n,35)
            v = pts[ord[firstpos[slot] + r]];
    }
    outF[row] = v;
}

__global__ void k_sentinel(float* __restrict__ out) { out[0] = 1e8f; }

extern "C" void kernel_launch(void* const* d_in, const int* in_sizes, int n_in,
                              void* d_out, int out_size, void* d_ws, size_t ws_size,
                              hipStream_t stream) {
    const float4* pts = (const float4*)d_in[0];
    float* out = (float*)d_out;
    uint32_t* ws = (uint32_t*)d_ws;

    if (ws_size < (size_t)WS_WORDS * sizeof(uint32_t)) {
        k_sentinel<<<1, 1, 0, stream>>>(out);
        return;
    }

    uint32_t* plin     = ws + WS_PLIN;
    uint32_t* ukey     = ws + WS_UKEY;
    uint32_t* bcnt     = ws + WS_BCNT;
    uint32_t* bstart   = ws + WS_BSTART;
    uint32_t* bcur     = ws + WS_BCUR;
    unsigned long long* pair = (unsigned long long*)(ws + WS_PAIR);
    uint32_t* ord      = ws + WS_ORD;
    uint32_t* lin_s    = ws + WS_LINS;
    uint32_t* sinc     = ws + WS_SINC;
    uint32_t* bs2      = ws + WS_BS2;
    uint32_t* firstpos = ws + WS_FIRST;
    uint32_t* cnt      = ws + WS_CNT;

    const int NBLK = (NPTS + 255) / 256;        // 782
    const int NSB  = (NPTS + 1023) / 1024;      // 196
    const int NFB  = (NROWS + 255) / 256;       // 27344

    // only scratch that needs zeroing: bcnt (+bstart overwritten) + bcur, 24 KB
    hipMemsetAsync(bcnt, 0, (size_t)(3 * NBUK) * sizeof(uint32_t), stream);

    k_key<<<NBLK, 256, 0, stream>>>(pts, plin, ukey, bcnt);
    k_bscan<<<1, 256, 0, stream>>>(bcnt, bstart);
    k_scatter<<<NBLK, 256, 0, stream>>>(ukey, bstart, bcur, pair);
    k_bsort<<<NBUK, 128, 0, stream>>>(bcnt, bstart, pair, plin, ord, lin_s);
    k_s1<<<NSB, 256, 0, stream>>>(lin_s, sinc, bs2);
    k_s2<<<1, 256, 0, stream>>>(bs2, NSB);
    k_first<<<NBLK, 256, 0, stream>>>(lin_s, sinc, bs2, firstpos, cnt, out);
    k_writeF<<<NFB, 256, 0, stream>>>(pts, firstpos, cnt, ord, bs2, (float4*)out);
}

// Round 8
// 96.227 us; speedup vs baseline: 1.3743x; 1.2405x over previous
//
#include <hip/hip_runtime.h>
#include <stdint.h>

// Problem constants
#define NPTS     200000
#define MAXP     35
#define MAXVOX   200000
#define GYZ      64000
#define GZD      40
#define TOTALLIN 90112000u        // invalid-point lin marker (== TOTAL in reference)

// Output layout (flat float32): features [200000*35*4] | coords [200000*3] | num [200000]
#define OFF_COORD 28000000
#define OFF_NUM   28600000

#define NBUK   2048               // top-11-bit buckets of biased wrapped key
#define BCAP   256                // slab capacity (Poisson λ≈98, max ≈150 — verified no overflow)
#define NROWS  (MAXVOX * MAXP)    // 7,000,000 feature rows, one float4 each
#define NSB    196                // ceil(NPTS/1024) scan blocks

// ws layout (uint32 words)
#define WS_PLIN   0               // 200000
#define WS_BCUR   200000          // 2048 (memset to 0 each call)
#define WS_BSTART 202048          // 2048
#define WS_PAIR   204096          // 2048*256 u64 slabs = 1,048,576 words (8B-aligned: even)
#define WS_ORD    1252672         // 200000
#define WS_LINS   1452672         // 200000
#define WS_SINC   1652672         // 200000
#define WS_BS2    1852672         // 256
#define WS_FIRST  1852928         // 200000
#define WS_CNT    2052928         // 200000
#define WS_WORDS  2252928         // 9,011,712 bytes

// Voxel id with XLA-simplifier semantics: (p-rmin)/vs -> (p-rmin)*(1/vs);
// f32 reciprocals of 0.05f / 0.1f constant-fold to EXACTLY 20.0f / 10.0f.
// (Verified green in R6/R7 together with wrapped-int32 sort keys.)
__device__ __forceinline__ uint32_t point_lin(const float4 p) {
    float fx = floorf((p.x -  0.0f) * 20.0f);
    float fy = floorf((p.y + 40.0f) * 20.0f);
    float fz = floorf((p.z +  3.0f) * 10.0f);
    if (fx < 0.0f || fx >= 1408.0f || fy < 0.0f || fy >= 1600.0f ||
        fz < 0.0f || fz >= 40.0f)
        return TOTALLIN;
    return (uint32_t)fx * (uint32_t)GYZ + (uint32_t)fy * (uint32_t)GZD + (uint32_t)fz;
}

// 1) fused: per-point lin + wrapped int32 key (jax x64-OFF) + direct slab scatter
__global__ void k_keyscatter(const float4* __restrict__ pts, uint32_t* __restrict__ plin,
                             uint32_t* __restrict__ bcur, unsigned long long* __restrict__ pair) {
    int i = blockIdx.x * blockDim.x + threadIdx.x;
    if (i >= NPTS) return;
    uint32_t lin = point_lin(pts[i]);
    plin[i] = lin;
    uint32_t key = lin * 200000u + (uint32_t)i;   // int32 wrap, bit-identical in uint32
    uint32_t uk = key ^ 0x80000000u;              // bias: unsigned order == signed order
    uint32_t b = uk >> 21;
    uint32_t j = atomicAdd(&bcur[b], 1u);
    if (j < BCAP)
        pair[(b << 8) + j] = ((unsigned long long)uk << 32) | (uint32_t)i;
}

// 2) exclusive scan of 2048 bucket counts -> dense output bases (1 block)
__global__ void k_bscan(const uint32_t* __restrict__ bcur, uint32_t* __restrict__ bstart) {
    __shared__ uint32_t s[256];
    __shared__ uint32_t run;
    int t = threadIdx.x;
    if (t == 0) run = 0;
    __syncthreads();
    for (int c = 0; c < NBUK / 256; c++) {
        int idx = c * 256 + t;
        uint32_t v = bcur[idx];
        s[t] = v; __syncthreads();
        for (int off = 1; off < 256; off <<= 1) {
            uint32_t x = (t >= off) ? s[t - off] : 0u;
            __syncthreads();
            s[t] += x; __syncthreads();
        }
        uint32_t incl = s[t];
        uint32_t tot  = s[255];
        uint32_t r    = run;
        bstart[idx] = r + incl - v;
        __syncthreads();
        if (t == 0) run = r + tot;
        __syncthreads();
    }
}

// 3) per-bucket bitonic sort of 256 padded u64 keys; write dense ord/lin_s
__global__ __launch_bounds__(128) void k_bsort(const uint32_t* __restrict__ bcur,
                                               const uint32_t* __restrict__ bstart,
                                               const unsigned long long* __restrict__ pair,
                                               const uint32_t* __restrict__ plin,
                                               uint32_t* __restrict__ ord,
                                               uint32_t* __restrict__ lin_s) {
    __shared__ unsigned long long sd[BCAP];
    int b = blockIdx.x, t = threadIdx.x;
    int n = (int)bcur[b];
    if (n > BCAP) n = BCAP;
    int base = (int)bstart[b];
    const unsigned long long* slab = pair + ((size_t)b << 8);
    for (int k = t; k < BCAP; k += 128)
        sd[k] = (k < n) ? slab[k] : ~0ULL;
    __syncthreads();
    for (int k = 2; k <= BCAP; k <<= 1) {
        for (int j = k >> 1; j > 0; j >>= 1) {
            int i = ((t & ~(j - 1)) << 1) | (t & (j - 1));
            int p = i | j;
            bool up = ((i & k) == 0);
            unsigned long long a = sd[i], c = sd[p];
            if ((a > c) == up) { sd[i] = c; sd[p] = a; }
            __syncthreads();
        }
    }
    for (int k = t; k < n; k += 128) {
        unsigned long long v = sd[k];
        uint32_t i = (uint32_t)v;
        ord[base + k] = i;
        lin_s[base + k] = plin[i];
    }
}

// 4) fused head-flag + per-1024-region inclusive scan + region sums
__global__ void k_s1(const uint32_t* __restrict__ lin_s, uint32_t* __restrict__ sinc,
                     uint32_t* __restrict__ bs2) {
    __shared__ uint32_t s[256];
    int b = blockIdx.x, t = threadIdx.x;
    int base = b * 1024 + t * 4;
    uint32_t f[4];
    uint32_t prev = (base > 0 && base - 1 < NPTS) ? lin_s[base - 1] : 0xFFFFFFFFu;
    uint32_t tsum = 0;
#pragma unroll
    for (int j = 0; j < 4; j++) {
        int pos = base + j;
        f[j] = 0u;
        if (pos < NPTS) {
            uint32_t lin = lin_s[pos];
            bool head = (lin != TOTALLIN) && (pos == 0 || lin != prev);
            f[j] = head ? 1u : 0u;
            prev = lin;
        }
        tsum += f[j];
    }
    s[t] = tsum; __syncthreads();
    for (int off = 1; off < 256; off <<= 1) {
        uint32_t x = (t >= off) ? s[t - off] : 0u;
        __syncthreads();
        s[t] += x; __syncthreads();
    }
    uint32_t incl = s[t];
    uint32_t running = incl - tsum;
#pragma unroll
    for (int j = 0; j < 4; j++) {
        int pos = base + j;
        running += f[j];
        if (pos < NPTS) sinc[pos] = running;   // inclusive within 1024-region
    }
    if (t == 255) bs2[b] = incl;               // region total
}

// 5) heads + padding, with region-offset scan fused (thread 0 folds 196 sums).
//    Heads: firstpos/cnt + coords/num. Padding (pos>=nun): zero coords/num AND cnt.
__global__ void k_first(const uint32_t* __restrict__ lin_s, const uint32_t* __restrict__ sinc,
                        const uint32_t* __restrict__ bs2, uint32_t* __restrict__ firstpos,
                        uint32_t* __restrict__ cnt, float* __restrict__ out) {
    __shared__ uint32_t sh[2];                 // [0]=excl prefix of this block's region, [1]=nunique
    int b = blockIdx.x, t = threadIdx.x;
    int pos = b * 256 + t;
    if (t == 0) {
        int region = (b * 256) >> 10;          // one region per 256-thread block
        uint32_t pre = 0, tot = 0;
        for (int r = 0; r < NSB; ++r) {
            uint32_t v = bs2[r];
            pre += (r < region) ? v : 0u;
            tot += v;
        }
        sh[0] = pre; sh[1] = tot;
    }
    __syncthreads();
    if (pos >= NPTS) return;
    uint32_t nun = sh[1];
    if ((uint32_t)pos >= nun) {                // padding slot (slot space == pos space)
        out[OFF_COORD + (size_t)pos * 3 + 0] = 0.0f;
        out[OFF_COORD + (size_t)pos * 3 + 1] = 0.0f;
        out[OFF_COORD + (size_t)pos * 3 + 2] = 0.0f;
        out[OFF_NUM + pos] = 0.0f;
        cnt[pos] = 0u;                         // writeF's guard for padding rows
    }
    uint32_t lin = lin_s[pos];
    if (lin == TOTALLIN) return;
    if (pos > 0 && lin == lin_s[pos - 1]) return;          // not a head
    uint32_t slot = sinc[pos] + sh[0] - 1u;
    int n = 1;
    while (pos + n < NPTS && lin_s[pos + n] == lin) ++n;   // run length (runs are short)
    firstpos[slot] = (uint32_t)pos;
    cnt[slot] = (uint32_t)n;
    int m = (n < MAXP) ? n : MAXP;
    out[OFF_COORD + (size_t)slot * 3 + 0] = (float)(lin / GYZ);
    out[OFF_COORD + (size_t)slot * 3 + 1] = (float)((lin % GYZ) / GZD);
    out[OFF_COORD + (size_t)slot * 3 + 2] = (float)(lin % GZD);
    out[OFF_NUM + slot] = (float)m;
}

// 6) features: one thread per row (= one float4); every row written exactly once
__global__ void k_writeF(const float4* __restrict__ pts, const uint32_t* __restrict__ firstpos,
                         const uint32_t* __restrict__ cnt, const uint32_t* __restrict__ ord,
                         float4* __restrict__ outF) {
    int row = blockIdx.x * blockDim.x + threadIdx.x;
    if (row >= NROWS) return;
    uint32_t slot = (uint32_t)row / 35u;       // magic-mul const division
    uint32_t r = (uint32_t)row - slot * 35u;
    float4 v = make_float4(0.0f, 0.0f, 0.0f, 0.0f);
    uint32_t n = cnt[slot];                    // 0 for padding slots
    if (r < n)                                 // r<=34 => r<n  <=>  r<min(n,35)
        v = pts[ord[firstpos[slot] + r]];
    outF[row] = v;
}

__global__ void k_sentinel(float* __restrict__ out) { out[0] = 1e8f; }

extern "C" void kernel_launch(void* const* d_in, const int* in_sizes, int n_in,
                              void* d_out, int out_size, void* d_ws, size_t ws_size,
                              hipStream_t stream) {
    const float4* pts = (const float4*)d_in[0];
    float* out = (float*)d_out;
    uint32_t* ws = (uint32_t*)d_ws;

    if (ws_size < (size_t)WS_WORDS * sizeof(uint32_t)) {
        k_sentinel<<<1, 1, 0, stream>>>(out);
        return;
    }

    uint32_t* plin     = ws + WS_PLIN;
    uint32_t* bcur     = ws + WS_BCUR;
    uint32_t* bstart   = ws + WS_BSTART;
    unsigned long long* pair = (unsigned long long*)(ws + WS_PAIR);
    uint32_t* ord      = ws + WS_ORD;
    uint32_t* lin_s    = ws + WS_LINS;
    uint32_t* sinc     = ws + WS_SINC;
    uint32_t* bs2      = ws + WS_BS2;
    uint32_t* firstpos = ws + WS_FIRST;
    uint32_t* cnt      = ws + WS_CNT;

    const int NBLK = (NPTS + 255) / 256;        // 782
    const int NFB  = (NROWS + 255) / 256;       // 27344

    hipMemsetAsync(bcur, 0, (size_t)NBUK * sizeof(uint32_t), stream);   // 8 KB

    k_keyscatter<<<NBLK, 256, 0, stream>>>(pts, plin, bcur, pair);
    k_bscan<<<1, 256, 0, stream>>>(bcur, bstart);
    k_bsort<<<NBUK, 128, 0, stream>>>(bcur, bstart, pair, plin, ord, lin_s);
    k_s1<<<NSB, 256, 0, stream>>>(lin_s, sinc, bs2);
    k_first<<<NBLK, 256, 0, stream>>>(lin_s, sinc, bs2, firstpos, cnt, out);
    k_writeF<<<NFB, 256, 0, stream>>>(pts, firstpos, cnt, ord, (float4*)out);
}

// Round 9
// 86.891 us; speedup vs baseline: 1.5219x; 1.1074x over previous
//
#include <hip/hip_runtime.h>
#include <stdint.h>

// Problem constants
#define NPTS     200000
#define MAXP     35
#define MAXVOX   200000
#define GYZ      64000
#define GZD      40
#define TOTALLIN 90112000u        // invalid-point lin marker (== TOTAL in reference)

// Output layout (flat float32): features [200000*35*4] | coords [200000*3] | num [200000]
#define OFF_COORD 28000000
#define OFF_NUM   28600000

#define NBUK   2048               // top-11-bit buckets of biased wrapped key
#define BCAP   256                // slab capacity (λ≈98, max≈145 — no overflow)
#define NROWS  (MAXVOX * MAXP)    // 7,000,000 feature rows, one float4 each
#define NSB    196                // ceil(NPTS/1024) scan regions

// ws layout (uint32 words)
#define WS_PLIN   0               // 200000
#define WS_BCUR   200000          // 2048 (memset to 0 each call)
#define WS_PAIR   202048          // 2048*256 u64 slabs = 1,048,576 words (byte off %8==0)
#define WS_ORD    1250624         // 200000
#define WS_LINS   1450624         // 200000
#define WS_SINC   1650624         // 200000
#define WS_BS2    1850624         // 256
#define WS_FIRST  1850880         // 200000
#define WS_CNT    2050880         // 200000
#define WS_WORDS  2250880         // 9,003,520 bytes

// Voxel id with XLA-simplifier semantics: (p-rmin)/vs -> (p-rmin)*(1/vs);
// f32 reciprocals of 0.05f / 0.1f constant-fold to EXACTLY 20.0f / 10.0f.
// (Verified green R6-R8 together with wrapped-int32 sort keys.)
__device__ __forceinline__ uint32_t point_lin(const float4 p) {
    float fx = floorf((p.x -  0.0f) * 20.0f);
    float fy = floorf((p.y + 40.0f) * 20.0f);
    float fz = floorf((p.z +  3.0f) * 10.0f);
    if (fx < 0.0f || fx >= 1408.0f || fy < 0.0f || fy >= 1600.0f ||
        fz < 0.0f || fz >= 40.0f)
        return TOTALLIN;
    return (uint32_t)fx * (uint32_t)GYZ + (uint32_t)fy * (uint32_t)GZD + (uint32_t)fz;
}

// 1) fused: per-point lin + wrapped int32 key (jax x64-OFF) + direct slab scatter.
//    pair low word = original index i: reproduces stable-argsort tie-break for
//    the ~5 expected wrapped-key collisions (birthday: 200k keys in 2^32).
__global__ void k_keyscatter(const float4* __restrict__ pts, uint32_t* __restrict__ plin,
                             uint32_t* __restrict__ bcur, unsigned long long* __restrict__ pair) {
    int i = blockIdx.x * blockDim.x + threadIdx.x;
    if (i >= NPTS) return;
    uint32_t lin = point_lin(pts[i]);
    plin[i] = lin;
    uint32_t key = lin * 200000u + (uint32_t)i;   // int32 wrap, bit-identical in uint32
    uint32_t uk = key ^ 0x80000000u;              // bias: unsigned order == signed order
    uint32_t b = uk >> 21;
    uint32_t j = atomicAdd(&bcur[b], 1u);
    if (j < BCAP)
        pair[(b << 8) + j] = ((unsigned long long)uk << 32) | (uint32_t)i;
}

// 2) per-bucket: fused exclusive-prefix (strided masked sum over bcur) +
//    adaptive bitonic sort (m=128 if n<=128 else 256) + dense ord/lin_s out.
__global__ __launch_bounds__(128) void k_bsort(const uint32_t* __restrict__ bcur,
                                               const unsigned long long* __restrict__ pair,
                                               const uint32_t* __restrict__ plin,
                                               uint32_t* __restrict__ ord,
                                               uint32_t* __restrict__ lin_s) {
    __shared__ unsigned long long sd[BCAP];
    __shared__ uint32_t red[128];
    int b = blockIdx.x, t = threadIdx.x;
    // bstart = sum of bcur[j], j < b (L2-hot; <=16 reads/thread)
    uint32_t part = 0;
    for (int j = t; j < b; j += 128) part += bcur[j];
    red[t] = part; __syncthreads();
    for (int off = 64; off > 0; off >>= 1) {
        if (t < off) red[t] += red[t + off];
        __syncthreads();
    }
    int base = (int)red[0];
    int n = (int)bcur[b];
    if (n > BCAP) n = BCAP;
    const unsigned long long* slab = pair + ((size_t)b << 8);
    int m = (n <= 128) ? 128 : BCAP;
    for (int k = t; k < m; k += 128)
        sd[k] = (k < n) ? slab[k] : ~0ULL;
    __syncthreads();
    int half = m >> 1;
    for (int k = 2; k <= m; k <<= 1) {
        for (int j = k >> 1; j > 0; j >>= 1) {
            if (t < half) {
                int i = ((t & ~(j - 1)) << 1) | (t & (j - 1));
                int p = i | j;
                bool up = ((i & k) == 0);
                unsigned long long a = sd[i], c = sd[p];
                if ((a > c) == up) { sd[i] = c; sd[p] = a; }
            }
            __syncthreads();
        }
    }
    for (int k = t; k < n; k += 128) {
        unsigned long long v = sd[k];
        uint32_t i = (uint32_t)v;
        ord[base + k] = i;
        lin_s[base + k] = plin[i];
    }
}

// 3) fused head-flag + per-1024-region inclusive scan + region sums
__global__ void k_s1(const uint32_t* __restrict__ lin_s, uint32_t* __restrict__ sinc,
                     uint32_t* __restrict__ bs2) {
    __shared__ uint32_t s[256];
    int b = blockIdx.x, t = threadIdx.x;
    int base = b * 1024 + t * 4;
    uint32_t f[4];
    uint32_t prev = (base > 0 && base - 1 < NPTS) ? lin_s[base - 1] : 0xFFFFFFFFu;
    uint32_t tsum = 0;
#pragma unroll
    for (int j = 0; j < 4; j++) {
        int pos = base + j;
        f[j] = 0u;
        if (pos < NPTS) {
            uint32_t lin = lin_s[pos];
            bool head = (lin != TOTALLIN) && (pos == 0 || lin != prev);
            f[j] = head ? 1u : 0u;
            prev = lin;
        }
        tsum += f[j];
    }
    s[t] = tsum; __syncthreads();
    for (int off = 1; off < 256; off <<= 1) {
        uint32_t x = (t >= off) ? s[t - off] : 0u;
        __syncthreads();
        s[t] += x; __syncthreads();
    }
    uint32_t incl = s[t];
    uint32_t running = incl - tsum;
#pragma unroll
    for (int j = 0; j < 4; j++) {
        int pos = base + j;
        running += f[j];
        if (pos < NPTS) sinc[pos] = running;   // inclusive within 1024-region
    }
    if (t == 255) bs2[b] = incl;               // region total
}

// 4) heads + padding, region-offset fold fused (thread 0 folds 196 sums).
//    Heads: firstpos/cnt + coords/num. Padding (pos>=nun): zero coords/num AND cnt.
__global__ void k_first(const uint32_t* __restrict__ lin_s, const uint32_t* __restrict__ sinc,
                        const uint32_t* __restrict__ bs2, uint32_t* __restrict__ firstpos,
                        uint32_t* __restrict__ cnt, float* __restrict__ out) {
    __shared__ uint32_t sh[2];                 // [0]=excl prefix of this block's region, [1]=nunique
    int b = blockIdx.x, t = threadIdx.x;
    int pos = b * 256 + t;
    if (t == 0) {
        int region = (b * 256) >> 10;          // region covering this block
        uint32_t pre = 0, tot = 0;
        for (int r = 0; r < NSB; ++r) {
            uint32_t v = bs2[r];
            pre += (r < region) ? v : 0u;
            tot += v;
        }
        sh[0] = pre; sh[1] = tot;
    }
    __syncthreads();
    if (pos >= NPTS) return;
    uint32_t nun = sh[1];
    if ((uint32_t)pos >= nun) {                // padding slot (slot space == pos space)
        out[OFF_COORD + (size_t)pos * 3 + 0] = 0.0f;
        out[OFF_COORD + (size_t)pos * 3 + 1] = 0.0f;
        out[OFF_COORD + (size_t)pos * 3 + 2] = 0.0f;
        out[OFF_NUM + pos] = 0.0f;
        cnt[pos] = 0u;                         // writeF's guard for padding rows
    }
    uint32_t lin = lin_s[pos];
    if (lin == TOTALLIN) return;
    if (pos > 0 && lin == lin_s[pos - 1]) return;          // not a head
    uint32_t slot = sinc[pos] + sh[0] - 1u;
    int n = 1;
    while (pos + n < NPTS && lin_s[pos + n] == lin) ++n;   // run length (runs are short)
    firstpos[slot] = (uint32_t)pos;
    cnt[slot] = (uint32_t)n;
    int m = (n < MAXP) ? n : MAXP;
    out[OFF_COORD + (size_t)slot * 3 + 0] = (float)(lin / GYZ);
    out[OFF_COORD + (size_t)slot * 3 + 1] = (float)((lin % GYZ) / GZD);
    out[OFF_COORD + (size_t)slot * 3 + 2] = (float)(lin % GZD);
    out[OFF_NUM + slot] = (float)m;
}

// 5) features: one thread per row (= one float4); every row written exactly once
__global__ void k_writeF(const float4* __restrict__ pts, const uint32_t* __restrict__ firstpos,
                         const uint32_t* __restrict__ cnt, const uint32_t* __restrict__ ord,
                         float4* __restrict__ outF) {
    int row = blockIdx.x * blockDim.x + threadIdx.x;
    if (row >= NROWS) return;
    uint32_t slot = (uint32_t)row / 35u;       // magic-mul const division
    uint32_t r = (uint32_t)row - slot * 35u;
    float4 v = make_float4(0.0f, 0.0f, 0.0f, 0.0f);
    uint32_t n = cnt[slot];                    // 0 for padding slots
    if (r < n)                                 // r<=34 => r<n  <=>  r<min(n,35)
        v = pts[ord[firstpos[slot] + r]];
    outF[row] = v;
}

__global__ void k_sentinel(float* __restrict__ out) { out[0] = 1e8f; }

extern "C" void kernel_launch(void* const* d_in, const int* in_sizes, int n_in,
                              void* d_out, int out_size, void* d_ws, size_t ws_size,
                              hipStream_t stream) {
    const float4* pts = (const float4*)d_in[0];
    float* out = (float*)d_out;
    uint32_t* ws = (uint32_t*)d_ws;

    if (ws_size < (size_t)WS_WORDS * sizeof(uint32_t)) {
        k_sentinel<<<1, 1, 0, stream>>>(out);
        return;
    }

    uint32_t* plin     = ws + WS_PLIN;
    uint32_t* bcur     = ws + WS_BCUR;
    unsigned long long* pair = (unsigned long long*)(ws + WS_PAIR);
    uint32_t* ord      = ws + WS_ORD;
    uint32_t* lin_s    = ws + WS_LINS;
    uint32_t* sinc     = ws + WS_SINC;
    uint32_t* bs2      = ws + WS_BS2;
    uint32_t* firstpos = ws + WS_FIRST;
    uint32_t* cnt      = ws + WS_CNT;

    const int NBLK = (NPTS + 255) / 256;        // 782
    const int NFB  = (NROWS + 255) / 256;       // 27344

    hipMemsetAsync(bcur, 0, (size_t)NBUK * sizeof(uint32_t), stream);   // 8 KB

    k_keyscatter<<<NBLK, 256, 0, stream>>>(pts, plin, bcur, pair);
    k_bsort<<<NBUK, 128, 0, stream>>>(bcur, pair, plin, ord, lin_s);
    k_s1<<<NSB, 256, 0, stream>>>(lin_s, sinc, bs2);
    k_first<<<NBLK, 256, 0, stream>>>(lin_s, sinc, bs2, firstpos, cnt, out);
    k_writeF<<<NFB, 256, 0, stream>>>(pts, firstpos, cnt, ord, (float4*)out);
}